// Round 6
// baseline (921.501 us; speedup 1.0000x reference)
//
#include <hip/hip_runtime.h>

// Problem constants
#define BQ   512   // batch
#define SEQ  128   // L
#define IND  256   // INPUT_DIM
#define POSD 32
#define EMB  512
#define NH   4
#define HDIM 128
#define OUTD 256
#define NBLK 256   // persistent grid size for front/tail

// ---------------------------------------------------------------------------
// One-shot software grid barrier. Each stage boundary uses a DISTINCT cell
// (128-B padded). Cells are zeroed by a hipMemsetAsync at the head of every
// kernel_launch call, so each cell is used exactly once per launch — no
// sense-reversal needed. Co-residency: 256 blocks x 256 thr, ~9 KB LDS,
// <=128 VGPR -> >=4 blocks/CU capacity, so all 256 blocks are resident and
// the barrier cannot deadlock.
// ---------------------------------------------------------------------------
__device__ __forceinline__ void gbar(unsigned* cells, int idx)
{
    __threadfence();               // publish this thread's prior global stores
    __syncthreads();
    if (threadIdx.x == 0) {
        unsigned* c = cells + idx * 32;
        __hip_atomic_fetch_add(c, 1u, __ATOMIC_ACQ_REL, __HIP_MEMORY_SCOPE_AGENT);
        while (__hip_atomic_load(c, __ATOMIC_ACQUIRE, __HIP_MEMORY_SCOPE_AGENT) < NBLK)
            __builtin_amdgcn_s_sleep(2);
    }
    __syncthreads();
    __threadfence();               // acq fence: drop stale cached lines
}

// ---------------------------------------------------------------------------
// 64x64 output tile GEMM (exact arithmetic of the round-4 PASSING kernel).
// A points at the tile origin rows [64][K]; B at [K][64] (BT=false) or
// [64 n-rows][K] (BT=true); C at the tile origin. bias = per-col ptr or null.
// ---------------------------------------------------------------------------
template<bool BT>
__device__ __forceinline__ void tile64(const float* __restrict__ A, int lda,
                                       const float* __restrict__ B, int ldb,
                                       int K,
                                       float* __restrict__ C, int ldc,
                                       const float* __restrict__ bias,
                                       float (*As)[68], float (*Bs)[68])
{
    const int tid = threadIdx.x;
    const int tx  = tid & 15;
    const int ty  = tid >> 4;
    const int bn  = tid & 63;
    const int bk  = tid >> 6;

    float acc[4][4] = {{0.f}};

    for (int k0 = 0; k0 < K; k0 += 16) {
        #pragma unroll
        for (int i = 0; i < 4; i++)
            As[tx][ty + i * 16] = A[(long)(ty + i * 16) * lda + (k0 + tx)];
        if (BT) {
            #pragma unroll
            for (int i = 0; i < 4; i++)
                Bs[tx][ty + i * 16] = B[(long)(ty + i * 16) * ldb + (k0 + tx)];
        } else {
            #pragma unroll
            for (int i = 0; i < 4; i++)
                Bs[bk + i * 4][bn] = B[(long)(k0 + bk + i * 4) * ldb + bn];
        }
        __syncthreads();
        #pragma unroll
        for (int kk = 0; kk < 16; kk++) {
            float a4[4], b4[4];
            *(float4*)a4 = *(const float4*)&As[kk][ty * 4];
            *(float4*)b4 = *(const float4*)&Bs[kk][tx * 4];
            #pragma unroll
            for (int i = 0; i < 4; i++)
                #pragma unroll
                for (int j = 0; j < 4; j++)
                    acc[i][j] = fmaf(a4[i], b4[j], acc[i][j]);
        }
        __syncthreads();
    }

    const int gn = tx * 4;
    #pragma unroll
    for (int i = 0; i < 4; i++) {
        const int gm = ty * 4 + i;
        float4 v;
        v.x = acc[i][0]; v.y = acc[i][1]; v.z = acc[i][2]; v.w = acc[i][3];
        if (bias) {
            const float4 bv = *(const float4*)(bias + gn);
            v.x += bv.x; v.y += bv.y; v.z += bv.z; v.w += bv.w;
        }
        *(float4*)&C[(long)gm * ldc + gn] = v;
    }
}

// ---------------------------------------------------------------------------
// FRONT persistent kernel: pos_pb | wfpq partials | reduce | Q+G1+G2 | tsp
// WfPQ is one contiguous [384][1536] buffer: rows 0..255 = Wf, 256..383 = PQ.
// G1_h = posv_h @ Wproj_h (128x512); G2_h = Wev_h @ Wproj_h (256x512)
// (ctx-through-proj fold: O1 = sum_h ATN_h@G1_h + U_h@G2_h + b_proj).
// ---------------------------------------------------------------------------
struct FrontP {
    const float *hist, *W_embed, *b_embed, *W_r, *W_attn, *b_attn, *W_proj;
    float *PB, *PART, *WfPQ, *Q, *G1, *G2, *T, *SP;
    unsigned *BAR;
};

__global__ __launch_bounds__(256)
void front_k(FrontP p)
{
    __shared__ float As[16][68];
    __shared__ float Bs[16][68];
    __shared__ float rr[POSD];
    const int bid = blockIdx.x;
    const int tid = threadIdx.x;

    // ---- S0: pos_pb (blocks 0..127, one position each) ----
    if (bid < SEQ) {
        if (tid < POSD) {
            const int pos = (SEQ - 1) - bid;   // flip axis 0
            float acc = 0.f;
            #pragma unroll
            for (int i = 0; i < POSD; i++) {
                float expo  = powf(10000.0f, (2.0f * i) / (float)POSD);
                float angle = (float)pos / expo;
                float Ri    = ((i & 1) == 0) ? sinf(angle) : cosf(angle);
                acc = fmaf(Ri, p.W_r[i * POSD + tid], acc);
            }
            rr[tid] = acc;
        }
        __syncthreads();
        for (int c = tid; c < EMB; c += 256) {
            float acc = p.b_embed[c];
            #pragma unroll
            for (int i = 0; i < POSD; i++)
                acc = fmaf(rr[i], p.W_embed[(IND + i) * EMB + c], acc);
            p.PB[bid * EMB + c] = acc;
        }
    }
    gbar(p.BAR, 0);

    // ---- S1: wfpq split-K partials: [4 ks][384][1536], 576 virtual tiles ----
    for (int t = bid; t < 576; t += NBLK) {
        const int ks = t / 144, r = t % 144;
        const int m0 = (r / 24) * 64, n0 = (r % 24) * 64, kb = ks * 128;
        const float* Arow = (m0 < 256) ? (p.W_embed + (long)m0 * 512)
                                       : (p.PB + (long)(m0 - 256) * 512);
        tile64<false>(Arow + kb, 512,
                      p.W_attn + (long)kb * 1536 + n0, 1536, 128,
                      p.PART + (long)ks * 589824 + (long)m0 * 1536 + n0, 1536,
                      nullptr, As, Bs);
    }
    gbar(p.BAR, 1);

    // ---- S2: reduce 4 slices -> WfPQ (+ b_attn on rows >= 256) ----
    for (int idx = bid * 256 + tid; idx < 147456; idx += 65536) {
        const long e = (long)idx * 4;
        float4 s = *(const float4*)(p.PART + e);
        #pragma unroll
        for (int sl = 1; sl < 4; sl++) {
            const float4 q = *(const float4*)(p.PART + (long)sl * 589824 + e);
            s.x += q.x; s.y += q.y; s.z += q.z; s.w += q.w;
        }
        const int row = (int)(e / 1536);
        if (row >= 256) {
            const int col = (int)(e - (long)row * 1536);
            const float4 bv = *(const float4*)(p.b_attn + col);
            s.x += bv.x; s.y += bv.y; s.z += bv.z; s.w += bv.w;
        }
        *(float4*)(p.WfPQ + e) = s;
    }
    gbar(p.BAR, 2);

    // ---- S3: Q (64 tiles, K=256) + G1 (64 tiles) + G2 (128 tiles) ----
    for (int t = bid; t < 256; t += NBLK) {
        if (t < 64) {
            const int m0 = (t >> 3) * 64, n0 = (t & 7) * 64;
            tile64<false>(p.hist + 127 * IND + (long)m0 * (SEQ * IND), SEQ * IND,
                          p.WfPQ + n0, 1536, 256,
                          p.Q + (long)m0 * 512 + n0, 512,
                          p.WfPQ + (long)(256 + 127) * 1536 + n0, As, Bs);
        } else if (t < 128) {
            const int i = t - 64, h = i >> 4, r2 = i & 15;
            const int m0 = (r2 >> 3) * 64, n0 = (r2 & 7) * 64;
            tile64<false>(p.WfPQ + 256 * 1536 + 1024 + h * 128 + (long)m0 * 1536, 1536,
                          p.W_proj + (long)h * 128 * 512 + n0, 512, 128,
                          p.G1 + (long)h * 65536 + (long)m0 * 512 + n0, 512,
                          nullptr, As, Bs);
        } else {
            const int i = t - 128, h = i >> 5, r2 = i & 31;
            const int m0 = (r2 >> 3) * 64, n0 = (r2 & 7) * 64;
            tile64<false>(p.WfPQ + 1024 + h * 128 + (long)m0 * 1536, 1536,
                          p.W_proj + (long)h * 128 * 512 + n0, 512, 128,
                          p.G2 + (long)h * 131072 + (long)m0 * 512 + n0, 512,
                          nullptr, As, Bs);
        }
    }
    gbar(p.BAR, 3);

    // ---- S4: tsp — T (128 tiles) and SP (64 tiles), B transposed ----
    for (int t = bid; t < 192; t += NBLK) {
        if (t < 128) {
            const int h = t >> 5, i = t & 31;
            const int m0 = (i >> 2) * 64, n0 = (i & 3) * 64;
            tile64<true>(p.Q + h * 128 + (long)m0 * 512, 512,
                         p.WfPQ + 512 + h * 128 + (long)n0 * 1536, 1536, 128,
                         p.T + (long)h * 131072 + (long)m0 * 256 + n0, 256,
                         nullptr, As, Bs);
        } else {
            const int i = t - 128, h = i >> 4, j = i & 15;
            const int m0 = (j >> 1) * 64, n0 = (j & 1) * 64;
            tile64<true>(p.Q + h * 128 + (long)m0 * 512, 512,
                         p.WfPQ + 256 * 1536 + 512 + h * 128 + (long)n0 * 1536, 1536, 128,
                         p.SP + (long)h * 65536 + (long)m0 * 128 + n0, 128,
                         nullptr, As, Bs);
        }
    }
}

// ---------------------------------------------------------------------------
// Per-batch attention for the last query row (UNCHANGED from the passing r4).
// ---------------------------------------------------------------------------
__global__ __launch_bounds__(512)
void attn_k(const float* __restrict__ hist,
            const float* __restrict__ T,    // [4][512][256]
            const float* __restrict__ SP,   // [4][512][128]
            float* __restrict__ ATN,        // [4][512][128]
            float* __restrict__ U)          // [4][512][256]
{
    const int b   = blockIdx.x;
    const int tid = threadIdx.x;

    __shared__ float x[SEQ][IND + 1];
    __shared__ float t[NH][IND];
    __shared__ float sc[NH][SEQ];
    __shared__ float tmp[NH][SEQ];

    const float4* src = (const float4*)(hist + (long)b * SEQ * IND);
    #pragma unroll
    for (int i = 0; i < 16; i++) {
        int idx = tid + i * 512;
        int k   = idx >> 6;
        int j4  = (idx & 63) << 2;
        float4 v = src[idx];
        x[k][j4 + 0] = v.x; x[k][j4 + 1] = v.y;
        x[k][j4 + 2] = v.z; x[k][j4 + 3] = v.w;
    }
    #pragma unroll
    for (int i = 0; i < 2; i++) {
        int idx = tid + i * 512;
        int h = idx >> 8, j = idx & 255;
        t[h][j] = T[(long)h * (BQ * IND) + (long)b * IND + j];
    }
    {
        int h = tid >> 7, k = tid & 127;
        sc[h][k] = SP[(long)h * (BQ * SEQ) + b * SEQ + k];
    }
    __syncthreads();

    const int h = tid >> 7;
    const int k = tid & 127;
    const float* xr = &x[k][0];
    const float* tr = &t[h][0];
    float sraw = 0.f;
    #pragma unroll 8
    for (int j = 0; j < IND; j++)
        sraw = fmaf(xr[j], tr[j], sraw);
    const float s = (sraw + sc[h][k]) * 0.08838834764831845f;

    tmp[h][k] = s;
    __syncthreads();
    for (int st = 64; st > 0; st >>= 1) {
        if (k < st) tmp[h][k] = fmaxf(tmp[h][k], tmp[h][k + st]);
        __syncthreads();
    }
    const float mx_ = tmp[h][0];
    __syncthreads();
    const float e = expf(s - mx_);
    tmp[h][k] = e;
    __syncthreads();
    for (int st = 64; st > 0; st >>= 1) {
        if (k < st) tmp[h][k] += tmp[h][k + st];
        __syncthreads();
    }
    const float a = e / tmp[h][0];
    sc[h][k] = a;
    ATN[(long)h * (BQ * SEQ) + b * SEQ + k] = a;
    __syncthreads();

    const int j  = tid & 255;
    const int hh = tid >> 8;
    const float* a0 = &sc[hh][0];
    const float* a1 = &sc[hh + 2][0];
    float u0 = 0.f, u1 = 0.f;
    #pragma unroll 4
    for (int kk = 0; kk < SEQ; kk++) {
        float xv = x[kk][j];
        u0 = fmaf(a0[kk], xv, u0);
        u1 = fmaf(a1[kk], xv, u1);
    }
    U[(long)hh       * (BQ * IND) + b * IND + j] = u0;
    U[(long)(hh + 2) * (BQ * IND) + b * IND + j] = u1;
}

// ---------------------------------------------------------------------------
// TAIL persistent kernel: O1 partials | reduce | X1 | X2 | XP partials | final
// O1 = sum_h ATN_h@G1_h + sum_{h,q} U_hq@G2_hq + b_proj   (12 K-chunks)
// ---------------------------------------------------------------------------
struct TailP {
    const float *hist, *W1, *b1, *W2, *b2, *W5, *b5, *W_skip, *b_skip, *b_proj;
    const float *ATN, *U, *G1, *G2;
    float *PART, *O1, *X1, *X2, *out;
    unsigned *BAR;
};

__global__ __launch_bounds__(256)
void tail_k(TailP p)
{
    __shared__ float As[16][68];
    __shared__ float Bs[16][68];
    __shared__ float red[8];
    const int bid = blockIdx.x;
    const int tid = threadIdx.x;

    // ---- T1: O1 partials [12][512][512], 768 virtual tiles ----
    for (int t = bid; t < 768; t += NBLK) {
        const int c = t / 64, r = t % 64;
        const int m0 = (r >> 3) * 64, n0 = (r & 7) * 64;
        const float* A; int lda; const float* B;
        if (c < 4) {
            A = p.ATN + (long)c * 65536 + (long)m0 * 128; lda = 128;
            B = p.G1 + (long)c * 65536 + n0;
        } else {
            const int h = (c - 4) >> 1, q = (c - 4) & 1;
            A = p.U + (long)h * 131072 + q * 128 + (long)m0 * 256; lda = 256;
            B = p.G2 + (long)h * 131072 + (long)q * 65536 + n0;
        }
        tile64<false>(A, lda, B, 512, 128,
                      p.PART + (long)c * 262144 + (long)m0 * 512 + n0, 512,
                      nullptr, As, Bs);
    }
    gbar(p.BAR, 8);

    // ---- T2: reduce 12 + b_proj -> O1 (65536 float4, one per thread) ----
    {
        const int idx = bid * 256 + tid;
        const long e = (long)idx * 4;
        float4 s = *(const float4*)(p.PART + e);
        #pragma unroll
        for (int sl = 1; sl < 12; sl++) {
            const float4 q = *(const float4*)(p.PART + (long)sl * 262144 + e);
            s.x += q.x; s.y += q.y; s.z += q.z; s.w += q.w;
        }
        const int col = (int)(e & 511);
        const float4 bv = *(const float4*)(p.b_proj + col);
        s.x += bv.x; s.y += bv.y; s.z += bv.z; s.w += bv.w;
        *(float4*)(p.O1 + e) = s;
    }
    gbar(p.BAR, 9);

    // ---- T3: X1 partials [4][512][512], 256 tiles ----
    for (int t = bid; t < 256; t += NBLK) {
        const int c = t >> 6, r = t & 63;
        const int m0 = (r >> 3) * 64, n0 = (r & 7) * 64;
        tile64<false>(p.O1 + c * 128 + (long)m0 * 512, 512,
                      p.W1 + (long)c * 128 * 512 + n0, 512, 128,
                      p.PART + (long)c * 262144 + (long)m0 * 512 + n0, 512,
                      nullptr, As, Bs);
    }
    gbar(p.BAR, 10);

    // ---- T4: reduce 4 + b1 + relu -> X1 ----
    {
        const int idx = bid * 256 + tid;
        const long e = (long)idx * 4;
        float4 s = *(const float4*)(p.PART + e);
        #pragma unroll
        for (int sl = 1; sl < 4; sl++) {
            const float4 q = *(const float4*)(p.PART + (long)sl * 262144 + e);
            s.x += q.x; s.y += q.y; s.z += q.z; s.w += q.w;
        }
        const int col = (int)(e & 511);
        const float4 bv = *(const float4*)(p.b1 + col);
        s.x = fmaxf(s.x + bv.x, 0.f); s.y = fmaxf(s.y + bv.y, 0.f);
        s.z = fmaxf(s.z + bv.z, 0.f); s.w = fmaxf(s.w + bv.w, 0.f);
        *(float4*)(p.X1 + e) = s;
    }
    gbar(p.BAR, 11);

    // ---- T5: X2 partials ----
    for (int t = bid; t < 256; t += NBLK) {
        const int c = t >> 6, r = t & 63;
        const int m0 = (r >> 3) * 64, n0 = (r & 7) * 64;
        tile64<false>(p.X1 + c * 128 + (long)m0 * 512, 512,
                      p.W2 + (long)c * 128 * 512 + n0, 512, 128,
                      p.PART + (long)c * 262144 + (long)m0 * 512 + n0, 512,
                      nullptr, As, Bs);
    }
    gbar(p.BAR, 12);

    // ---- T6: reduce 4 + b2 + relu -> X2 ----
    {
        const int idx = bid * 256 + tid;
        const long e = (long)idx * 4;
        float4 s = *(const float4*)(p.PART + e);
        #pragma unroll
        for (int sl = 1; sl < 4; sl++) {
            const float4 q = *(const float4*)(p.PART + (long)sl * 262144 + e);
            s.x += q.x; s.y += q.y; s.z += q.z; s.w += q.w;
        }
        const int col = (int)(e & 511);
        const float4 bv = *(const float4*)(p.b2 + col);
        s.x = fmaxf(s.x + bv.x, 0.f); s.y = fmaxf(s.y + bv.y, 0.f);
        s.z = fmaxf(s.z + bv.z, 0.f); s.w = fmaxf(s.w + bv.w, 0.f);
        *(float4*)(p.X2 + e) = s;
    }
    gbar(p.BAR, 13);

    // ---- T7: XP partials [6][512][256]: X2@W5 (4) + hist0@W_skip (2) ----
    for (int t = bid; t < 192; t += NBLK) {
        const int c = t >> 5, r = t & 31;
        const int m0 = (r >> 2) * 64, n0 = (r & 3) * 64;
        const float* A; int lda; const float* B;
        if (c < 4) {
            A = p.X2 + c * 128 + (long)m0 * 512; lda = 512;
            B = p.W5 + (long)c * 128 * 256 + n0;
        } else if (c == 4) {
            A = p.hist + (long)m0 * (SEQ * IND); lda = SEQ * IND;
            B = p.W_skip + n0;
        } else {
            A = p.hist + 128 + (long)m0 * (SEQ * IND); lda = SEQ * IND;
            B = p.W_skip + 128 * 256 + n0;
        }
        tile64<false>(A, lda, B, 256, 128,
                      p.PART + (long)c * 131072 + (long)m0 * 256 + n0, 256,
                      nullptr, As, Bs);
    }
    gbar(p.BAR, 14);

    // ---- T8: final — rows 2*bid, 2*bid+1: relu(sum6+biases), minmax norm ----
    for (int rw = 0; rw < 2; rw++) {
        const int row = bid * 2 + rw;
        float v = p.b5[tid] + p.b_skip[tid];
        #pragma unroll
        for (int s = 0; s < 6; s++)
            v += p.PART[(long)s * 131072 + (long)row * 256 + tid];
        v = fmaxf(v, 0.f);

        float lo = v, hi = v;
        #pragma unroll
        for (int off = 32; off > 0; off >>= 1) {
            lo = fminf(lo, __shfl_down(lo, off));
            hi = fmaxf(hi, __shfl_down(hi, off));
        }
        if ((tid & 63) == 0) { red[tid >> 6] = lo; red[4 + (tid >> 6)] = hi; }
        __syncthreads();
        if (tid == 0) {
            float l0 = red[0], h0 = red[4];
            for (int i = 1; i < 4; i++) { l0 = fminf(l0, red[i]); h0 = fmaxf(h0, red[4 + i]); }
            red[0] = l0; red[4] = h0;
        }
        __syncthreads();
        const float lo0 = red[0], hi0 = red[4];
        p.out[(long)row * 256 + tid] = 2.f * (v - lo0) / (hi0 - lo0) - 1.f;
        __syncthreads();   // protect red[] before next row
    }
}

// ---------------------------------------------------------------------------
extern "C" void kernel_launch(void* const* d_in, const int* in_sizes, int n_in,
                              void* d_out, int out_size, void* d_ws, size_t ws_size,
                              hipStream_t stream)
{
    const float* hist    = (const float*)d_in[0];
    // d_in[1] end_pos: provably unused — for the last query row (q=L-1),
    // k_idx - q_idx <= 0 < end_pos (end_pos >= 1), so the mask never fires.
    const float* W_embed = (const float*)d_in[2];
    const float* b_embed = (const float*)d_in[3];
    const float* W_r     = (const float*)d_in[4];
    const float* W_attn  = (const float*)d_in[5];
    const float* b_attn  = (const float*)d_in[6];
    const float* W_proj  = (const float*)d_in[7];
    const float* b_proj  = (const float*)d_in[8];
    const float* W_skip  = (const float*)d_in[9];
    const float* b_skip  = (const float*)d_in[10];
    const float* W1      = (const float*)d_in[11];
    const float* b1      = (const float*)d_in[12];
    const float* W2      = (const float*)d_in[13];
    const float* b2      = (const float*)d_in[14];
    const float* W5      = (const float*)d_in[15];
    const float* b5      = (const float*)d_in[16];
    float* out = (float*)d_out;
    float* ws  = (float*)d_ws;
    (void)in_sizes; (void)n_in; (void)out_size; (void)ws_size;

    // workspace layout (float offsets)
    float* PB   = ws;                 //  65536   [128][512]
    float* WfPQ = ws + 65536;         // 589824   rows 0-255 Wf | 256-383 PQ, ld 1536
    float* Q    = ws + 655360;        // 262144   [512][512]
    float* G1   = ws + 917504;        // 262144   [4][128][512]
    float* G2   = ws + 1179648;       // 524288   [4][256][512]
    float* T    = ws + 1703936;       // 524288   [4][512][256]
    float* SP   = ws + 2228224;       // 262144   [4][512][128]
    float* ATN  = ws + 2490368;       // 262144   [4][512][128]
    float* U    = ws + 2752512;       // 524288   [4][512][256]
    float* PART = ws + 3276800;       // 3145728  max(4x384x1536, 12x512x512)
    float* O1   = ws + 6422528;       // 262144
    float* X1   = ws + 6684672;       // 262144
    float* X2   = ws + 6946816;       // 262144
    unsigned* BAR = (unsigned*)(ws + 7208960);   // 16 cells x 128 B

    // zero the one-shot barrier cells (re-done every call; ws is re-poisoned)
    hipMemsetAsync(BAR, 0, 16 * 32 * sizeof(unsigned), stream);

    FrontP fp{hist, W_embed, b_embed, W_r, W_attn, b_attn, W_proj,
              PB, PART, WfPQ, Q, G1, G2, T, SP, BAR};
    front_k<<<NBLK, 256, 0, stream>>>(fp);

    attn_k<<<BQ, 512, 0, stream>>>(hist, T, SP, ATN, U);

    TailP tp{hist, W1, b1, W2, b2, W5, b5, W_skip, b_skip, b_proj,
             ATN, U, G1, G2, PART, O1, X1, X2, out, BAR};
    tail_k<<<NBLK, 256, 0, stream>>>(tp);
}

// Round 7
// 252.330 us; speedup vs baseline: 3.6520x; 3.6520x over previous
//
#include <hip/hip_runtime.h>

// Problem constants
#define BQ   512   // batch
#define SEQ  128   // L
#define IND  256   // INPUT_DIM
#define POSD 32
#define EMB  512
#define NH   4
#define HDIM 128
#define OUTD 256

// ---------------------------------------------------------------------------
// 64x64 output tile GEMM (exact arithmetic of the r4/r6 PASSING kernels).
// A points at the tile origin rows [64][K]; B at [K][64] (BT=false) or
// [64 n-rows][K] (BT=true); C at the tile origin. bias = per-col ptr or null.
// ---------------------------------------------------------------------------
template<bool BT>
__device__ __forceinline__ void tile64(const float* __restrict__ A, int lda,
                                       const float* __restrict__ B, int ldb,
                                       int K,
                                       float* __restrict__ C, int ldc,
                                       const float* __restrict__ bias,
                                       float (*As)[68], float (*Bs)[68])
{
    const int tid = threadIdx.x;
    const int tx  = tid & 15;
    const int ty  = tid >> 4;
    const int bn  = tid & 63;
    const int bk  = tid >> 6;

    float acc[4][4] = {{0.f}};

    for (int k0 = 0; k0 < K; k0 += 16) {
        #pragma unroll
        for (int i = 0; i < 4; i++)
            As[tx][ty + i * 16] = A[(long)(ty + i * 16) * lda + (k0 + tx)];
        if (BT) {
            #pragma unroll
            for (int i = 0; i < 4; i++)
                Bs[tx][ty + i * 16] = B[(long)(ty + i * 16) * ldb + (k0 + tx)];
        } else {
            #pragma unroll
            for (int i = 0; i < 4; i++)
                Bs[bk + i * 4][bn] = B[(long)(k0 + bk + i * 4) * ldb + bn];
        }
        __syncthreads();
        #pragma unroll
        for (int kk = 0; kk < 16; kk++) {
            float a4[4], b4[4];
            *(float4*)a4 = *(const float4*)&As[kk][ty * 4];
            *(float4*)b4 = *(const float4*)&Bs[kk][tx * 4];
            #pragma unroll
            for (int i = 0; i < 4; i++)
                #pragma unroll
                for (int j = 0; j < 4; j++)
                    acc[i][j] = fmaf(a4[i], b4[j], acc[i][j]);
        }
        __syncthreads();
    }

    const int gn = tx * 4;
    #pragma unroll
    for (int i = 0; i < 4; i++) {
        const int gm = ty * 4 + i;
        float4 v;
        v.x = acc[i][0]; v.y = acc[i][1]; v.z = acc[i][2]; v.w = acc[i][3];
        if (bias) {
            const float4 bv = *(const float4*)(bias + gn);
            v.x += bv.x; v.y += bv.y; v.z += bv.z; v.w += bv.w;
        }
        *(float4*)&C[(long)gm * ldc + gn] = v;
    }
}

// ---------------------------------------------------------------------------
// pos_pb: sinusoid rel-pos -> r = flip(enc)@W_r -> PB = r@W_embed[256:]+b_embed
// (r4, passed)
// ---------------------------------------------------------------------------
__global__ __launch_bounds__(256)
void pos_pb_k(const float* __restrict__ W_r, const float* __restrict__ W_embed,
              const float* __restrict__ b_embed, float* __restrict__ PB)
{
    __shared__ float rr[POSD];
    const int p   = blockIdx.x;        // 0..127
    const int tid = threadIdx.x;

    if (tid < POSD) {
        const int pos = (SEQ - 1) - p;  // flip axis 0
        float acc = 0.f;
        #pragma unroll
        for (int i = 0; i < POSD; i++) {
            float expo  = powf(10000.0f, (2.0f * i) / (float)POSD);
            float angle = (float)pos / expo;
            float Ri    = ((i & 1) == 0) ? sinf(angle) : cosf(angle);
            acc = fmaf(Ri, W_r[i * POSD + tid], acc);
        }
        rr[tid] = acc;
    }
    __syncthreads();

    for (int c = tid; c < EMB; c += 256) {
        float acc = b_embed[c];
        #pragma unroll
        for (int i = 0; i < POSD; i++)
            acc = fmaf(rr[i], W_embed[(IND + i) * EMB + c], acc);
        PB[p * EMB + c] = acc;
    }
}

// ---------------------------------------------------------------------------
// wfpq split-K partials: [4 ks][384][1536] (r4, passed)
// rows 0..255 = W_embed[0:256]@W_attn chunk; rows 256..383 = PB@W_attn chunk
// ---------------------------------------------------------------------------
__global__ __launch_bounds__(256)
void wfpq_sk_k(const float* __restrict__ W_embed, const float* __restrict__ PB,
               const float* __restrict__ W_attn, float* __restrict__ P)
{
    __shared__ float As[16][68];
    __shared__ float Bs[16][68];
    const int ks  = blockIdx.z;          // 0..3, K chunk base = ks*128
    const int kb  = ks * 128;
    const int m0  = blockIdx.y * 64;     // combined row 0..383
    const int n0  = blockIdx.x * 64;
    const float* Arow = (m0 < 256) ? (W_embed + (long)m0 * 512)
                                   : (PB + (long)(m0 - 256) * 512);
    tile64<false>(Arow + kb, 512,
                  W_attn + (long)kb * 1536 + n0, 1536, 128,
                  P + (long)ks * 589824 + (long)m0 * 1536 + n0, 1536,
                  nullptr, As, Bs);
}

// ---------------------------------------------------------------------------
// Generic partial reduce (r4, passed): C[e] = act(sum_s P[s][e] + bias if row>=start)
// ---------------------------------------------------------------------------
template<bool RELU>
__global__ __launch_bounds__(256)
void reduce_k(const float* __restrict__ P, long pStep, int nsl,
              const float* __restrict__ bias, int biasStartRow, int ldn,
              float* __restrict__ C)
{
    const long e = ((long)blockIdx.x * 256 + threadIdx.x) * 4;
    float4 s = *(const float4*)(P + e);
    for (int i = 1; i < nsl; i++) {
        const float4 p = *(const float4*)(P + (long)i * pStep + e);
        s.x += p.x; s.y += p.y; s.z += p.z; s.w += p.w;
    }
    if (bias) {
        const int row = (int)(e / ldn);
        if (row >= biasStartRow) {
            const int col = (int)(e % ldn);
            const float4 bv = *(const float4*)(bias + col);
            s.x += bv.x; s.y += bv.y; s.z += bv.z; s.w += bv.w;
        }
    }
    if (RELU) {
        s.x = fmaxf(s.x, 0.f); s.y = fmaxf(s.y, 0.f);
        s.z = fmaxf(s.z, 0.f); s.w = fmaxf(s.w, 0.f);
    }
    *(float4*)(C + e) = s;
}

// ---------------------------------------------------------------------------
// Q + G1 + G2 fused dispatch (r6 S3 body, HW-verified): 256 blocks.
//   t<64  : Q = hist[:,127,:]@Wf[:, :512] + PQ[127,:512]   (K=256)
//   t<128 : G1_h = posv_h @ Wproj_h  (128x512 per head)
//   else  : G2_h = Wev_h  @ Wproj_h  (256x512 per head)
// ---------------------------------------------------------------------------
__global__ __launch_bounds__(256)
void qg_k(const float* __restrict__ hist, const float* __restrict__ WfPQ,
          const float* __restrict__ W_proj,
          float* __restrict__ Q, float* __restrict__ G1, float* __restrict__ G2)
{
    __shared__ float As[16][68];
    __shared__ float Bs[16][68];
    const int t = blockIdx.x;
    if (t < 64) {
        const int m0 = (t >> 3) * 64, n0 = (t & 7) * 64;
        tile64<false>(hist + 127 * IND + (long)m0 * (SEQ * IND), SEQ * IND,
                      WfPQ + n0, 1536, 256,
                      Q + (long)m0 * 512 + n0, 512,
                      WfPQ + (long)(256 + 127) * 1536 + n0, As, Bs);
    } else if (t < 128) {
        const int i = t - 64, h = i >> 4, r2 = i & 15;
        const int m0 = (r2 >> 3) * 64, n0 = (r2 & 7) * 64;
        tile64<false>(WfPQ + 256 * 1536 + 1024 + h * 128 + (long)m0 * 1536, 1536,
                      W_proj + (long)h * 128 * 512 + n0, 512, 128,
                      G1 + (long)h * 65536 + (long)m0 * 512 + n0, 512,
                      nullptr, As, Bs);
    } else {
        const int i = t - 128, h = i >> 5, r2 = i & 31;
        const int m0 = (r2 >> 3) * 64, n0 = (r2 & 7) * 64;
        tile64<false>(WfPQ + 1024 + h * 128 + (long)m0 * 1536, 1536,
                      W_proj + (long)h * 128 * 512 + n0, 512, 128,
                      G2 + (long)h * 131072 + (long)m0 * 512 + n0, 512,
                      nullptr, As, Bs);
    }
}

// ---------------------------------------------------------------------------
// T + SP fused (r6 S4 body, HW-verified): 192 blocks, B transposed.
// ---------------------------------------------------------------------------
__global__ __launch_bounds__(256)
void tsp_k(const float* __restrict__ Q, const float* __restrict__ WfPQ,
           float* __restrict__ T, float* __restrict__ SP)
{
    __shared__ float As[16][68];
    __shared__ float Bs[16][68];
    const int t = blockIdx.x;
    if (t < 128) {
        const int h = t >> 5, i = t & 31;
        const int m0 = (i >> 2) * 64, n0 = (i & 3) * 64;
        tile64<true>(Q + h * 128 + (long)m0 * 512, 512,
                     WfPQ + 512 + h * 128 + (long)n0 * 1536, 1536, 128,
                     T + (long)h * 131072 + (long)m0 * 256 + n0, 256,
                     nullptr, As, Bs);
    } else {
        const int i = t - 128, h = i >> 4, j = i & 15;
        const int m0 = (j >> 1) * 64, n0 = (j & 1) * 64;
        tile64<true>(Q + h * 128 + (long)m0 * 512, 512,
                     WfPQ + 256 * 1536 + 512 + h * 128 + (long)n0 * 1536, 1536, 128,
                     SP + (long)h * 65536 + (long)m0 * 128 + n0, 128,
                     nullptr, As, Bs);
    }
}

// ---------------------------------------------------------------------------
// Per-batch attention for the last query row (UNCHANGED; passed r4 + r6).
// ---------------------------------------------------------------------------
__global__ __launch_bounds__(512)
void attn_k(const float* __restrict__ hist,
            const float* __restrict__ T,    // [4][512][256]
            const float* __restrict__ SP,   // [4][512][128]
            float* __restrict__ ATN,        // [4][512][128]
            float* __restrict__ U)          // [4][512][256]
{
    const int b   = blockIdx.x;
    const int tid = threadIdx.x;

    __shared__ float x[SEQ][IND + 1];
    __shared__ float t[NH][IND];
    __shared__ float sc[NH][SEQ];
    __shared__ float tmp[NH][SEQ];

    const float4* src = (const float4*)(hist + (long)b * SEQ * IND);
    #pragma unroll
    for (int i = 0; i < 16; i++) {
        int idx = tid + i * 512;
        int k   = idx >> 6;
        int j4  = (idx & 63) << 2;
        float4 v = src[idx];
        x[k][j4 + 0] = v.x; x[k][j4 + 1] = v.y;
        x[k][j4 + 2] = v.z; x[k][j4 + 3] = v.w;
    }
    #pragma unroll
    for (int i = 0; i < 2; i++) {
        int idx = tid + i * 512;
        int h = idx >> 8, j = idx & 255;
        t[h][j] = T[(long)h * (BQ * IND) + (long)b * IND + j];
    }
    {
        int h = tid >> 7, k = tid & 127;
        sc[h][k] = SP[(long)h * (BQ * SEQ) + b * SEQ + k];
    }
    __syncthreads();

    const int h = tid >> 7;
    const int k = tid & 127;
    const float* xr = &x[k][0];
    const float* tr = &t[h][0];
    float sraw = 0.f;
    #pragma unroll 8
    for (int j = 0; j < IND; j++)
        sraw = fmaf(xr[j], tr[j], sraw);
    const float s = (sraw + sc[h][k]) * 0.08838834764831845f;

    tmp[h][k] = s;
    __syncthreads();
    for (int st = 64; st > 0; st >>= 1) {
        if (k < st) tmp[h][k] = fmaxf(tmp[h][k], tmp[h][k + st]);
        __syncthreads();
    }
    const float mx_ = tmp[h][0];
    __syncthreads();
    const float e = expf(s - mx_);
    tmp[h][k] = e;
    __syncthreads();
    for (int st = 64; st > 0; st >>= 1) {
        if (k < st) tmp[h][k] += tmp[h][k + st];
        __syncthreads();
    }
    const float a = e / tmp[h][0];
    sc[h][k] = a;
    ATN[(long)h * (BQ * SEQ) + b * SEQ + k] = a;
    __syncthreads();

    const int j  = tid & 255;
    const int hh = tid >> 8;
    const float* a0 = &sc[hh][0];
    const float* a1 = &sc[hh + 2][0];
    float u0 = 0.f, u1 = 0.f;
    #pragma unroll 4
    for (int kk = 0; kk < SEQ; kk++) {
        float xv = x[kk][j];
        u0 = fmaf(a0[kk], xv, u0);
        u1 = fmaf(a1[kk], xv, u1);
    }
    U[(long)hh       * (BQ * IND) + b * IND + j] = u0;
    U[(long)(hh + 2) * (BQ * IND) + b * IND + j] = u1;
}

// ---------------------------------------------------------------------------
// O1 split-K partials [12][512][512] (r6 T1 mapping, HW-verified).
// O1 = sum_h ATN_h@G1_h + sum_{h,q} U_hq@G2_hq  (+ b_proj in reduce)
// grid (8, 8, 12)
// ---------------------------------------------------------------------------
__global__ __launch_bounds__(256)
void o1_sk_k(const float* __restrict__ ATN, const float* __restrict__ U,
             const float* __restrict__ G1, const float* __restrict__ G2,
             float* __restrict__ P)
{
    __shared__ float As[16][68];
    __shared__ float Bs[16][68];
    const int c  = blockIdx.z;
    const int m0 = blockIdx.y * 64, n0 = blockIdx.x * 64;
    const float* A; int lda; const float* B;
    if (c < 4) {
        A = ATN + (long)c * 65536 + (long)m0 * 128; lda = 128;
        B = G1 + (long)c * 65536 + n0;
    } else {
        const int h = (c - 4) >> 1, q = (c - 4) & 1;
        A = U + (long)h * 131072 + q * 128 + (long)m0 * 256; lda = 256;
        B = G2 + (long)h * 131072 + (long)q * 65536 + n0;
    }
    tile64<false>(A, lda, B, 512, 128,
                  P + (long)c * 262144 + (long)m0 * 512 + n0, 512,
                  nullptr, As, Bs);
}

// ---------------------------------------------------------------------------
// MLP split-K x8 (K=64 chunks): P[c] = A[:, c*64:+64] @ W[c*64:+64, :]
// grid (8, 8, 8); used for X1 and X2 (512x512x512).
// ---------------------------------------------------------------------------
__global__ __launch_bounds__(256)
void mlp_sk_k(const float* __restrict__ A0, const float* __restrict__ W,
              float* __restrict__ P)
{
    __shared__ float As[16][68];
    __shared__ float Bs[16][68];
    const int c  = blockIdx.z;
    const int m0 = blockIdx.y * 64, n0 = blockIdx.x * 64;
    tile64<false>(A0 + c * 64 + (long)m0 * 512, 512,
                  W + (long)c * 64 * 512 + n0, 512, 64,
                  P + (long)c * 262144 + (long)m0 * 512 + n0, 512,
                  nullptr, As, Bs);
}

// ---------------------------------------------------------------------------
// XP partials [6][512][256] (r6 T7 mapping, HW-verified):
// X2@W5 (4 chunks) + hist[:,0,:]@W_skip (2 chunks). grid (4, 8, 6).
// ---------------------------------------------------------------------------
__global__ __launch_bounds__(256)
void xp_sk_k(const float* __restrict__ X2, const float* __restrict__ W5,
             const float* __restrict__ hist, const float* __restrict__ W_skip,
             float* __restrict__ P)
{
    __shared__ float As[16][68];
    __shared__ float Bs[16][68];
    const int c  = blockIdx.z;
    const int m0 = blockIdx.y * 64, n0 = blockIdx.x * 64;
    const float* A; int lda; const float* B;
    if (c < 4) {
        A = X2 + c * 128 + (long)m0 * 512; lda = 512;
        B = W5 + (long)c * 128 * 256 + n0;
    } else if (c == 4) {
        A = hist + (long)m0 * (SEQ * IND); lda = SEQ * IND;
        B = W_skip + n0;
    } else {
        A = hist + 128 + (long)m0 * (SEQ * IND); lda = SEQ * IND;
        B = W_skip + 128 * 256 + n0;
    }
    tile64<false>(A, lda, B, 256, 128,
                  P + (long)c * 131072 + (long)m0 * 256 + n0, 256,
                  nullptr, As, Bs);
}

// ---------------------------------------------------------------------------
// Final (r4, passed): v = relu(sum_{s<6} P[s] + b5 + b_skip); minmax norm.
// ---------------------------------------------------------------------------
__global__ __launch_bounds__(256)
void final_k(const float* __restrict__ P,
             const float* __restrict__ b5, const float* __restrict__ b_skip,
             float* __restrict__ out)
{
    const int b = blockIdx.x, tid = threadIdx.x;
    const long e = (long)b * OUTD + tid;
    float v = b5[tid] + b_skip[tid];
    #pragma unroll
    for (int s = 0; s < 6; s++)
        v += P[(long)s * (BQ * OUTD) + e];
    v = fmaxf(v, 0.f);

    __shared__ float mn[4], mx[4];
    float lo = v, hi = v;
    #pragma unroll
    for (int off = 32; off > 0; off >>= 1) {
        lo = fminf(lo, __shfl_down(lo, off));
        hi = fmaxf(hi, __shfl_down(hi, off));
    }
    const int w = tid >> 6;
    if ((tid & 63) == 0) { mn[w] = lo; mx[w] = hi; }
    __syncthreads();
    if (tid == 0) {
        float l0 = mn[0], h0 = mx[0];
        for (int i = 1; i < 4; i++) { l0 = fminf(l0, mn[i]); h0 = fmaxf(h0, mx[i]); }
        mn[0] = l0; mx[0] = h0;
    }
    __syncthreads();
    const float lo0 = mn[0], hi0 = mx[0];
    out[e] = 2.f * (v - lo0) / (hi0 - lo0) - 1.f;
}

// ---------------------------------------------------------------------------
extern "C" void kernel_launch(void* const* d_in, const int* in_sizes, int n_in,
                              void* d_out, int out_size, void* d_ws, size_t ws_size,
                              hipStream_t stream)
{
    const float* hist    = (const float*)d_in[0];
    // d_in[1] end_pos: provably unused — for the last query row (q=L-1),
    // k_idx - q_idx <= 0 < end_pos (end_pos >= 1), so the mask never fires.
    const float* W_embed = (const float*)d_in[2];
    const float* b_embed = (const float*)d_in[3];
    const float* W_r     = (const float*)d_in[4];
    const float* W_attn  = (const float*)d_in[5];
    const float* b_attn  = (const float*)d_in[6];
    const float* W_proj  = (const float*)d_in[7];
    const float* b_proj  = (const float*)d_in[8];
    const float* W_skip  = (const float*)d_in[9];
    const float* b_skip  = (const float*)d_in[10];
    const float* W1      = (const float*)d_in[11];
    const float* b1      = (const float*)d_in[12];
    const float* W2      = (const float*)d_in[13];
    const float* b2      = (const float*)d_in[14];
    const float* W5      = (const float*)d_in[15];
    const float* b5      = (const float*)d_in[16];
    float* out = (float*)d_out;
    float* ws  = (float*)d_ws;
    (void)in_sizes; (void)n_in; (void)out_size; (void)ws_size;

    // workspace layout (float offsets) — same as r6 (HW-verified addressing)
    float* PB   = ws;                 //  65536   [128][512]
    float* WfPQ = ws + 65536;         // 589824   rows 0-255 Wf | 256-383 PQ, ld 1536
    float* Q    = ws + 655360;        // 262144   [512][512]
    float* G1   = ws + 917504;        // 262144   [4][128][512]
    float* G2   = ws + 1179648;       // 524288   [4][256][512]
    float* T    = ws + 1703936;       // 524288   [4][512][256]
    float* SP   = ws + 2228224;       // 262144   [4][512][128]
    float* ATN  = ws + 2490368;       // 262144   [4][512][128]
    float* U    = ws + 2752512;       // 524288   [4][512][256]
    float* PART = ws + 3276800;       // 3145728  max(4x384x1536, 12x512x512)
    float* O1   = ws + 6422528;       // 262144
    float* X1   = ws + 6684672;       // 262144
    float* X2   = ws + 6946816;       // 262144

    // 1) positional basis + pos_bias
    pos_pb_k<<<SEQ, 256, 0, stream>>>(W_r, W_embed, b_embed, PB);
    // 2) WfPQ split-K partials  (576 blocks)
    wfpq_sk_k<<<dim3(24, 6, 4), 256, 0, stream>>>(W_embed, PB, W_attn, PART);
    // 3) reduce -> WfPQ (+ b_attn on rows >= 256)
    reduce_k<false><<<576, 256, 0, stream>>>(PART, 589824, 4, b_attn, 256, 1536, WfPQ);
    // 4) Q + G1 + G2 (256 blocks)
    qg_k<<<256, 256, 0, stream>>>(hist, WfPQ, W_proj, Q, G1, G2);
    // 5) T + SP (192 blocks)
    tsp_k<<<192, 256, 0, stream>>>(Q, WfPQ, T, SP);
    // 6) attention (512 blocks)
    attn_k<<<BQ, 512, 0, stream>>>(hist, T, SP, ATN, U);
    // 7) O1 split-K partials (768 blocks)
    o1_sk_k<<<dim3(8, 8, 12), 256, 0, stream>>>(ATN, U, G1, G2, PART);
    // 8) reduce 12 + b_proj -> O1
    reduce_k<false><<<256, 256, 0, stream>>>(PART, 262144, 12, b_proj, 0, 512, O1);
    // 9) X1 split-K x8 partials (512 blocks)
    mlp_sk_k<<<dim3(8, 8, 8), 256, 0, stream>>>(O1, W1, PART);
    // 10) reduce 8 + b1 + relu -> X1
    reduce_k<true><<<256, 256, 0, stream>>>(PART, 262144, 8, b1, 0, 512, X1);
    // 11) X2 split-K x8 partials (512 blocks)
    mlp_sk_k<<<dim3(8, 8, 8), 256, 0, stream>>>(X1, W2, PART);
    // 12) reduce 8 + b2 + relu -> X2
    reduce_k<true><<<256, 256, 0, stream>>>(PART, 262144, 8, b2, 0, 512, X2);
    // 13) XP partials: X2@W5 (4) + hist0@W_skip (2)  (192 blocks)
    xp_sk_k<<<dim3(4, 8, 6), 256, 0, stream>>>(X2, W5, hist, W_skip, PART);
    // 14) final: sum 6 partials + biases, relu, minmax normalize
    final_k<<<BQ, 256, 0, stream>>>(PART, b5, b_skip, out);
}